// Round 7
// baseline (240.836 us; speedup 1.0000x reference)
//
#include <hip/hip_runtime.h>

// Single-pass cumulative max along H for x:(32,1,1024,1024) fp32, registers
// only. Round-6 post-mortem: conflicts 0, WRITE exact, but 2.25 TB/s —
// limited by (a) prefetch depth 1 (loads drained within the same chunk ->
// ~50% memory duty cycle) and (b) 128 B request granule at 4 KB stride.
// This round: 512-thread blocks, strip = 16 float4 = 256 B granule (2x),
// prefetch depth 2 (triple buffer: chunk c consumed 2 iters after issue ->
// loads never block), 2-step shuffle scan + 8-entry LDS wave exchange
// (bank pattern 2-way aliased = free), 1 barrier/chunk, parity buffers.
// 512 blocks x 8 waves = 16 waves/CU; ~8 KB/wave continuously in flight.

constexpr int B = 32;
constexpr int H = 1024;
constexpr int W = 1024;
constexpr int ROW4 = W / 4;          // 256 float4 per row
constexpr int SW4 = 16;              // strip width: 16 float4 = 64 floats = 256 B
constexpr int NSTRIP = ROW4 / SW4;   // 16 strips per b -> 512 blocks
constexpr int NT = 512;              // threads per block (8 waves)
constexpr int NWAVE = NT / 64;       // 8
constexpr int NSEG = NT / SW4;       // 32 h-segments per chunk
constexpr int R = 4;                 // rows per thread per chunk
constexpr int CH = NSEG * R;         // 128 rows per chunk
constexpr int NCHUNK = H / CH;       // 8

__device__ __forceinline__ float4 max4(float4 a, float4 b) {
    return make_float4(fmaxf(a.x, b.x), fmaxf(a.y, b.y),
                       fmaxf(a.z, b.z), fmaxf(a.w, b.w));
}

__device__ __forceinline__ float4 shflup4(float4 v, int d) {
    float4 r;
    r.x = __shfl_up(v.x, d, 64);
    r.y = __shfl_up(v.y, d, 64);
    r.z = __shfl_up(v.z, d, 64);
    r.w = __shfl_up(v.w, d, 64);
    return r;
}

__global__ __launch_bounds__(512, 4) void cummax_sp2(const float* __restrict__ xf,
                                                     float* __restrict__ of) {
    __shared__ float4 wavetot[2][NWAVE][SW4];   // 4 KB

    const int tid = threadIdx.x;
    const int lane = tid & 63;
    const int wid = tid >> 6;             // wave 0..7
    const int w = tid & (SW4 - 1);        // float4-col within strip, 0..15
    const int hsegG = tid >> 4;           // h-segment in chunk, 0..31
    const int hseg_l = (tid >> 4) & 3;    // h-segment within wave, 0..3

    const int b = blockIdx.x >> 4;
    const int strip = blockIdx.x & (NSTRIP - 1);
    const float4* x4 = (const float4*)xf;
    float4* o4 = (float4*)of;
    const size_t tbase = (size_t)b * (H * ROW4) + (size_t)strip * SW4 + w;

    const float ninf = -__builtin_inff();
    const float4 ninf4 = make_float4(ninf, ninf, ninf, ninf);
    float4 carry = ninf4;

    float4 c0[R], c1[R], c2[R];

    // chunk c, this thread's rows: c*CH + hsegG*R + r
#define LDCHUNK(c, dst)                                                      \
    _Pragma("unroll")                                                        \
    for (int r = 0; r < R; ++r)                                              \
        dst[r] = x4[tbase + (size_t)((c) * CH + hsegG * R + r) * ROW4];

    LDCHUNK(0, c0);
    LDCHUNK(1, c1);

#pragma unroll
    for (int c = 0; c < NCHUNK; ++c) {
        // prefetch 2 chunks ahead — consumed two iterations from now
        if (c + 2 < NCHUNK) { LDCHUNK(c + 2, c2); }

        // this thread's segment max
        float4 m = max4(max4(c0[0], c0[1]), max4(c0[2], c0[3]));

        // inclusive scan over the wave's 4 h-segments (stride 16 lanes)
        float4 incl = m;
        { float4 t = shflup4(incl, 16); if (lane >= 16) incl = max4(incl, t); }
        { float4 t = shflup4(incl, 32); if (lane >= 32) incl = max4(incl, t); }
        float4 ew = shflup4(incl, 16);
        float4 excl = (hseg_l == 0) ? ninf4 : ew;

        // wave totals -> LDS (lanes 48..63 hold them)
        if (hseg_l == 3) wavetot[c & 1][wid][w] = incl;
        __syncthreads();

        float4 crosspre = carry;
        float4 tot = carry;
#pragma unroll
        for (int w2 = 0; w2 < NWAVE; ++w2) {
            float4 v = wavetot[c & 1][w2][w];
            if (w2 < wid) crosspre = max4(crosspre, v);
            tot = max4(tot, v);
        }
        carry = tot;

        // apply + store
        float4 a = max4(crosspre, excl);
#pragma unroll
        for (int r = 0; r < R; ++r) {
            a = max4(a, c0[r]);
            o4[tbase + (size_t)(c * CH + hsegG * R + r) * ROW4] = a;
        }

        // rotate buffers (renamed away by full unroll)
#pragma unroll
        for (int r = 0; r < R; ++r) { c0[r] = c1[r]; c1[r] = c2[r]; }
    }
#undef LDCHUNK
}

extern "C" void kernel_launch(void* const* d_in, const int* in_sizes, int n_in,
                              void* d_out, int out_size, void* d_ws, size_t ws_size,
                              hipStream_t stream) {
    const float* x = (const float*)d_in[0];
    float* out = (float*)d_out;
    cummax_sp2<<<B * NSTRIP, NT, 0, stream>>>(x, out);
}